// Round 1
// baseline (2094.706 us; speedup 1.0000x reference)
//
#include <hip/hip_runtime.h>
#include <math.h>

#define NJ 17
#define DD 128
#define TT 512
#define HH 16
#define HD 8
#define CC 256
#define NEG_INF -9e15f

// ws layout (float offsets)
#define WS_CONVW 0               // [256*256] conv_w scaled by BN
#define WS_WQT   65536           // [128*128] (h*8+e)*128+d, scaled by 1/sqrt(8)
#define WS_WKT   81920
#define WS_WVT   98304
#define WS_MOFF  114688          // [16*17*17] additive mask offsets
#define WS_BIAS  119312          // [256] fused BN bias
#define WS_TOTAL 119568

__global__ __launch_bounds__(256) void prep_kernel(
        const float* __restrict__ adj,
        const float* __restrict__ wq,
        const float* __restrict__ wk,
        const float* __restrict__ wv,
        const float* __restrict__ adj2,
        const float* __restrict__ conv_w,
        const float* __restrict__ gamma,
        const float* __restrict__ beta,
        const float* __restrict__ mean,
        const float* __restrict__ var,
        float* __restrict__ ws) {
    int g = blockIdx.x * 256 + threadIdx.x;
    if (g < 65536) {
        int o = g >> 8;
        float sg = gamma[o] * rsqrtf(var[o] + 1e-5f);
        ws[WS_CONVW + g] = conv_w[g] * sg;
        return;
    }
    g -= 65536;
    if (g < 3 * 16384) {
        int mat = g / 16384;
        int i = g - mat * 16384;         // i = he*128 + d
        int he = i >> 7, d = i & 127;
        const float* src = (mat == 0) ? wq : ((mat == 1) ? wk : wv);
        float scale = (mat == 0) ? 0.35355339059327373f : 1.0f;
        int h = he >> 3, e = he & 7;
        ws[WS_WQT + g] = src[(h * DD + d) * HD + e] * scale;
        return;
    }
    g -= 3 * 16384;
    if (g < HH * NJ * NJ) {
        int h = g / (NJ * NJ);
        int r = g - h * NJ * NJ;
        int n = r / NJ, m = r - n * NJ;
        float a1 = adj[n * NJ + m] + adj2[(h * NJ + n) * NJ + m];
        float a2 = adj[m * NJ + n] + adj2[(h * NJ + m) * NJ + n];
        ws[WS_MOFF + g] = (0.5f * (a1 + a2) > 0.f) ? 0.f : NEG_INF;
        return;
    }
    g -= HH * NJ * NJ;
    if (g < CC) {
        float sg = gamma[g] * rsqrtf(var[g] + 1e-5f);
        ws[WS_BIAS + g] = beta[g] - mean[g] * sg;
    }
}

__global__ __launch_bounds__(256) void gab_main(
        const float* __restrict__ x,
        const float* __restrict__ ws,
        float* __restrict__ out) {
    const int t = blockIdx.x;
    const int b = blockIdx.y;
    const int tid = threadIdx.x;

    // cs: [0..127]=xp, [128..255]=attn out. stride 260 => 16B-aligned rows, 2-way bank alias (free)
    __shared__ float cs[NJ][260];
    __shared__ float qs[NJ][132];
    __shared__ float ks[NJ][132];
    __shared__ float vs[NJ][132];

    // ---- Phase 0: load x[b,:,t,:] -> cs[n][d] ----
    const float* xb = x + (size_t)b * (DD * TT * NJ) + (size_t)t * NJ;
    for (int i = tid; i < NJ * DD; i += 256) {
        int d = i / NJ;
        int n = i - d * NJ;
        cs[n][d] = xb[(size_t)d * (TT * NJ) + n];
    }
    __syncthreads();

    // ---- Phase 1: QKV projection. thread = (he, n-group). W rows in registers. ----
    {
        const int he = tid & 127;
        const int ng = tid >> 7;          // wave-uniform
        const int n0 = ng * 8;            // group 0: n 0..8, group 1: n 8..16 (n=8 duplicated, same value)
        const float* wqr = ws + WS_WQT + he * DD;
        const float* wkr = ws + WS_WKT + he * DD;
        const float* wvr = ws + WS_WVT + he * DD;
        float aq[9], ak[9], av[9];
#pragma unroll
        for (int j = 0; j < 9; ++j) { aq[j] = 0.f; ak[j] = 0.f; av[j] = 0.f; }

        for (int kc = 0; kc < DD; kc += 16) {
            float wqf[16], wkf[16], wvf[16];
#pragma unroll
            for (int u = 0; u < 4; ++u) {
                *(float4*)&wqf[4 * u] = *(const float4*)(wqr + kc + 4 * u);
                *(float4*)&wkf[4 * u] = *(const float4*)(wkr + kc + 4 * u);
                *(float4*)&wvf[4 * u] = *(const float4*)(wvr + kc + 4 * u);
            }
#pragma unroll
            for (int j = 0; j < 9; ++j) {
                int n = n0 + j;
                float xf[16];
#pragma unroll
                for (int u = 0; u < 4; ++u)
                    *(float4*)&xf[4 * u] = *(const float4*)&cs[n][kc + 4 * u];
#pragma unroll
                for (int u = 0; u < 16; ++u) {
                    aq[j] += xf[u] * wqf[u];
                    ak[j] += xf[u] * wkf[u];
                    av[j] += xf[u] * wvf[u];
                }
            }
        }
#pragma unroll
        for (int j = 0; j < 9; ++j) {
            int n = n0 + j;
            qs[n][he] = aq[j];
            ks[n][he] = ak[j];
            vs[n][he] = av[j];
        }
    }
    __syncthreads();

    // ---- Phase 2: attention per (h,n) ----
    for (int item = tid; item < HH * NJ; item += 256) {
        int h = item / NJ;
        int n = item - h * NJ;
        const float* mo = ws + WS_MOFF + (h * NJ + n) * NJ;
        float qv[8];
#pragma unroll
        for (int u = 0; u < 2; ++u)
            *(float4*)&qv[4 * u] = *(const float4*)&qs[n][h * 8 + 4 * u];

        float s[NJ];
        float mx = -3.4e38f;
#pragma unroll
        for (int m = 0; m < NJ; ++m) {
            float kf[8];
#pragma unroll
            for (int u = 0; u < 2; ++u)
                *(float4*)&kf[4 * u] = *(const float4*)&ks[m][h * 8 + 4 * u];
            float acc = 0.f;
#pragma unroll
            for (int e2 = 0; e2 < 8; ++e2) acc += qv[e2] * kf[e2];
            acc += mo[m];
            s[m] = acc;
            mx = fmaxf(mx, acc);
        }
        float sum = 0.f;
#pragma unroll
        for (int m = 0; m < NJ; ++m) {
            float p = __expf(s[m] - mx);
            s[m] = p;
            sum += p;
        }
        float inv = 1.0f / sum;
        float ov[8];
#pragma unroll
        for (int e2 = 0; e2 < 8; ++e2) ov[e2] = 0.f;
#pragma unroll
        for (int m = 0; m < NJ; ++m) {
            float p = s[m] * inv;
            float vf[8];
#pragma unroll
            for (int u = 0; u < 2; ++u)
                *(float4*)&vf[4 * u] = *(const float4*)&vs[m][h * 8 + 4 * u];
#pragma unroll
            for (int e2 = 0; e2 < 8; ++e2) ov[e2] += p * vf[e2];
        }
#pragma unroll
        for (int e2 = 0; e2 < 8; ++e2) cs[n][DD + h * 8 + e2] = ov[e2];
    }
    __syncthreads();

    // ---- Phase 3: conv1x1 + BN + ReLU, thread = output channel o ----
    {
        const int o = tid;
        const float* wr = ws + WS_CONVW + o * CC;
        float bo = ws[WS_BIAS + o];
        float acc[NJ];
#pragma unroll
        for (int n = 0; n < NJ; ++n) acc[n] = bo;
        for (int c = 0; c < CC; c += 4) {
            float4 w4 = *(const float4*)(wr + c);
#pragma unroll
            for (int n = 0; n < NJ; ++n) {
                float4 c4 = *(const float4*)&cs[n][c];
                acc[n] += c4.x * w4.x + c4.y * w4.y + c4.z * w4.z + c4.w * w4.w;
            }
        }
        float* ob = out + (size_t)b * (CC * TT * NJ) + (size_t)o * (TT * NJ) + (size_t)t * NJ;
#pragma unroll
        for (int n = 0; n < NJ; ++n) ob[n] = fmaxf(acc[n], 0.f);
    }
}

extern "C" void kernel_launch(void* const* d_in, const int* in_sizes, int n_in,
                              void* d_out, int out_size, void* d_ws, size_t ws_size,
                              hipStream_t stream) {
    const float* x      = (const float*)d_in[0];
    const float* adj    = (const float*)d_in[1];
    const float* wq     = (const float*)d_in[2];
    const float* wk     = (const float*)d_in[3];
    const float* wv     = (const float*)d_in[4];
    const float* adj2   = (const float*)d_in[5];
    const float* conv_w = (const float*)d_in[6];
    const float* gamma  = (const float*)d_in[7];
    const float* beta   = (const float*)d_in[8];
    const float* mean   = (const float*)d_in[9];
    const float* var    = (const float*)d_in[10];
    float* ws   = (float*)d_ws;
    float* outp = (float*)d_out;

    const int B = in_sizes[0] / (DD * TT * NJ);

    prep_kernel<<<(WS_TOTAL + 255) / 256, 256, 0, stream>>>(
        adj, wq, wk, wv, adj2, conv_w, gamma, beta, mean, var, ws);

    dim3 grid(TT, B);
    gab_main<<<grid, 256, 0, stream>>>(x, ws, outp);
}

// Round 2
// 635.876 us; speedup vs baseline: 3.2942x; 3.2942x over previous
//
#include <hip/hip_runtime.h>
#include <hip/hip_bf16.h>
#include <math.h>

#define NJ 17
#define DD 128
#define TT 512
#define HH 16
#define CC 256
#define NEG_INF -9e15f

typedef __attribute__((ext_vector_type(8))) short short8;
typedef __attribute__((ext_vector_type(4))) float floatx4;
typedef _Float16 h8 __attribute__((ext_vector_type(8)));

// ws BYTE offsets
#define WB_CONV 0            // bf16[65536]  conv_w*bnscale, fragment order (16 nt x 8 ks x 64 lane x 8)
#define WB_QKV  131072       // bf16[49152]  [Wq|Wk|Wv] cols, fragment order (24 nt x 4 ks x 64 lane x 8)
#define WB_MOFF 229376       // f32[16*17*17] additive mask offsets
#define WB_BIAS 247872       // f32[256]     fused BN bias
#define PREP_ITEMS (65536 + 49152 + 4624 + 256)

__global__ __launch_bounds__(256) void prep_kernel(
        const float* __restrict__ adj,
        const float* __restrict__ wq,
        const float* __restrict__ wk,
        const float* __restrict__ wv,
        const float* __restrict__ adj2,
        const float* __restrict__ conv_w,
        const float* __restrict__ gamma,
        const float* __restrict__ beta,
        const float* __restrict__ mean,
        const float* __restrict__ var,
        char* __restrict__ ws) {
    int g = blockIdx.x * 256 + threadIdx.x;
    if (g < 65536) {
        // conv fragments: idx = ((nt*8+ks)*64+lane)*8+j ; o = nt*16+(lane&15), c = ks*32+(lane>>4)*8+j
        int j = g & 7, lane = (g >> 3) & 63, kn = g >> 9;
        int ks = kn & 7, nt = kn >> 3;
        int o = nt * 16 + (lane & 15);
        int c = ks * 32 + ((lane >> 4) & 3) * 8 + j;
        float sg = gamma[o] * rsqrtf(var[o] + 1e-5f);
        ((__hip_bfloat16*)(ws + WB_CONV))[g] = __float2bfloat16(conv_w[o * CC + c] * sg);
        return;
    }
    g -= 65536;
    if (g < 49152) {
        // qkv fragments: idx = ((nt*4+ks)*64+lane)*8+j ; n = nt*16+(lane&15), k = ks*32+(lane>>4)*8+j
        int j = g & 7, lane = (g >> 3) & 63, kn = g >> 9;
        int ks = kn & 3, nt = kn >> 2;            // nt 0..23 over 384 cols: [q|k|v]
        int n = nt * 16 + (lane & 15);
        int k = ks * 32 + ((lane >> 4) & 3) * 8 + j;
        int mat = n >> 7;                          // 0=q 1=k 2=v
        int wcol = n & 127;
        int h = wcol >> 3, e = wcol & 7;
        const float* src = (mat == 0) ? wq : ((mat == 1) ? wk : wv);
        float v = src[(h * DD + k) * 8 + e];       // (H,D,hd) layout
        if (mat == 0) v *= 0.35355339059327373f;   // 1/sqrt(8) folded into Wq
        ((__hip_bfloat16*)(ws + WB_QKV))[g] = __float2bfloat16(v);
        return;
    }
    g -= 49152;
    if (g < HH * NJ * NJ) {
        int h = g / (NJ * NJ);
        int r = g - h * NJ * NJ;
        int n = r / NJ, m = r - n * NJ;
        float a1 = adj[n * NJ + m] + adj2[(h * NJ + n) * NJ + m];
        float a2 = adj[m * NJ + n] + adj2[(h * NJ + m) * NJ + n];
        ((float*)(ws + WB_MOFF))[g] = (0.5f * (a1 + a2) > 0.f) ? 0.f : NEG_INF;
        return;
    }
    g -= HH * NJ * NJ;
    if (g < CC) {
        float sg = gamma[g] * rsqrtf(var[g] + 1e-5f);
        ((float*)(ws + WB_BIAS))[g] = beta[g] - mean[g] * sg;
    }
}

__global__ __launch_bounds__(256, 4) void gab_main(
        const float* __restrict__ x,
        const char* __restrict__ ws,
        float* __restrict__ out) {
    // t-swizzle: XCD x gets a contiguous t-range so adjacent write runs merge in one L2
    const int tp = blockIdx.x;                       // 0..255 (token pairs)
    const int t0 = 2 * ((tp & 7) * 32 + (tp >> 3));
    const int b = blockIdx.y;
    const int tid = threadIdx.x;
    const int lane = tid & 63;
    const int wave = tid >> 6;
    const int l15 = lane & 15;
    const int lq = lane >> 4;

    // cat: rows 0..33 = [xp_bf16 (128) | attn_bf16 (128)], rows 34..47 zero pad for M-tiles
    __shared__ __align__(16) __hip_bfloat16 cat[48][264];   // stride 528 B: 16B-aligned, 2-bank advance
    __shared__ __align__(16) _Float16 qkv[3][34][128];      // f16 q,k,v

    // ---- Phase 0: stage xp -> cat[row][d] (row = lt*17+n), zero pad rows ----
    const float* xb = x + (size_t)b * DD * TT * NJ + (size_t)t0 * NJ;
    for (int i = tid; i < DD * 17; i += 256) {
        int d = i / 17;
        int j = 2 * (i - d * 17);                   // 17 float2 cover j=0..33
        float2 f = *(const float2*)(xb + (size_t)d * (TT * NJ) + j);
        cat[j][d] = __float2bfloat16(f.x);
        cat[j + 1][d] = __float2bfloat16(f.y);
    }
    {
        uint4 z = make_uint4(0, 0, 0, 0);
        for (int i = tid; i < 448; i += 256) {      // rows 34..47, cols 0..255 as 16B chunks
            int r = 34 + (i >> 5);
            int c16 = i & 31;
            *(uint4*)((char*)&cat[r][0] + c16 * 16) = z;
        }
    }
    __syncthreads();

    // ---- Phase 1: QKV GEMM via MFMA. wave w owns Ntiles w*6..w*6+5 of 24 (cols: q|k|v) ----
    {
        const short8* bbase = (const short8*)(ws + WB_QKV);
        const int nt0 = wave * 6;
        for (int i = 0; i < 6; ++i) {
            const int nt = nt0 + i;
            floatx4 acc0 = {0.f, 0.f, 0.f, 0.f}, acc1 = acc0, acc2 = acc0;
            const short8* bp = bbase + (nt * 4) * 64 + lane;
#pragma unroll
            for (int ks = 0; ks < 4; ++ks) {
                short8 bf = bp[ks * 64];
                const int k0 = ks * 32 + lq * 8;
                short8 a0 = *(const short8*)&cat[l15][k0];
                short8 a1 = *(const short8*)&cat[16 + l15][k0];
                short8 a2 = *(const short8*)&cat[32 + l15][k0];
                acc0 = __builtin_amdgcn_mfma_f32_16x16x32_bf16(a0, bf, acc0, 0, 0, 0);
                acc1 = __builtin_amdgcn_mfma_f32_16x16x32_bf16(a1, bf, acc1, 0, 0, 0);
                acc2 = __builtin_amdgcn_mfma_f32_16x16x32_bf16(a2, bf, acc2, 0, 0, 0);
            }
            const int col = nt * 16 + l15;
            const int mat = col >> 7;
            const int mc = col & 127;
            const int rbase = lq * 4;
#pragma unroll
            for (int r = 0; r < 4; ++r) {
                qkv[mat][rbase + r][mc] = (_Float16)acc0[r];        // rows 0..15
                qkv[mat][16 + rbase + r][mc] = (_Float16)acc1[r];   // rows 16..31
                int row2 = 32 + rbase + r;
                if (row2 < 34) qkv[mat][row2][mc] = (_Float16)acc2[r];
            }
        }
    }
    __syncthreads();

    // ---- Phase 2: attention per (t,h,n), fp32 accumulate from f16 (v_fma_mix) ----
    for (int it = tid; it < 2 * HH * NJ; it += 256) {
        const int t = it / (HH * NJ);
        const int r2 = it - t * (HH * NJ);
        const int h = r2 / NJ;
        const int n = r2 - h * NJ;
        const float* mo = (const float*)(ws + WB_MOFF) + (h * NJ + n) * NJ;
        const h8 qv = *(const h8*)&qkv[0][t * NJ + n][h * 8];
        float s[NJ];
        float mx = -3.4e38f;
#pragma unroll
        for (int m = 0; m < NJ; ++m) {
            const h8 kv = *(const h8*)&qkv[1][t * NJ + m][h * 8];
            float a = mo[m];
#pragma unroll
            for (int e = 0; e < 8; ++e) a += (float)qv[e] * (float)kv[e];
            s[m] = a;
            mx = fmaxf(mx, a);
        }
        float sum = 0.f;
#pragma unroll
        for (int m = 0; m < NJ; ++m) {
            float p = __expf(s[m] - mx);
            s[m] = p;
            sum += p;
        }
        const float inv = 1.0f / sum;
        float ov[8];
#pragma unroll
        for (int e = 0; e < 8; ++e) ov[e] = 0.f;
#pragma unroll
        for (int m = 0; m < NJ; ++m) {
            const h8 vv = *(const h8*)&qkv[2][t * NJ + m][h * 8];
            const float p = s[m];
#pragma unroll
            for (int e = 0; e < 8; ++e) ov[e] += p * (float)vv[e];
        }
        const int row = t * NJ + n;
#pragma unroll
        for (int e = 0; e < 8; ++e)
            cat[row][128 + h * 8 + e] = __float2bfloat16(ov[e] * inv);
    }
    __syncthreads();

    // ---- Phase 3: conv1x1 GEMM via MFMA + BN bias + ReLU. wave w owns Ntiles w*4..w*4+3 ----
    {
        const short8* cbase = (const short8*)(ws + WB_CONV);
        const float* biasp = (const float*)(ws + WB_BIAS);
        const int nt0 = wave * 4;
        for (int i = 0; i < 4; ++i) {
            const int nt = nt0 + i;
            floatx4 acc0 = {0.f, 0.f, 0.f, 0.f}, acc1 = acc0, acc2 = acc0;
            const short8* bp = cbase + (nt * 8) * 64 + lane;
#pragma unroll
            for (int ks = 0; ks < 8; ++ks) {
                short8 bf = bp[ks * 64];
                const int k0 = ks * 32 + lq * 8;
                short8 a0 = *(const short8*)&cat[l15][k0];
                short8 a1 = *(const short8*)&cat[16 + l15][k0];
                short8 a2 = *(const short8*)&cat[32 + l15][k0];
                acc0 = __builtin_amdgcn_mfma_f32_16x16x32_bf16(a0, bf, acc0, 0, 0, 0);
                acc1 = __builtin_amdgcn_mfma_f32_16x16x32_bf16(a1, bf, acc1, 0, 0, 0);
                acc2 = __builtin_amdgcn_mfma_f32_16x16x32_bf16(a2, bf, acc2, 0, 0, 0);
            }
            const int o = nt * 16 + l15;
            const float bias = biasp[o];
            const size_t ob = ((size_t)b * CC + o) * (TT * NJ) + (size_t)t0 * NJ;
            const int rbase = lq * 4;
#pragma unroll
            for (int r = 0; r < 4; ++r) {
                out[ob + rbase + r] = fmaxf(acc0[r] + bias, 0.f);           // rows 0..15
                out[ob + 16 + rbase + r] = fmaxf(acc1[r] + bias, 0.f);      // rows 16..31
                int row2 = 32 + rbase + r;
                if (row2 < 34) out[ob + row2] = fmaxf(acc2[r] + bias, 0.f); // rows 32..33
            }
        }
    }
}

extern "C" void kernel_launch(void* const* d_in, const int* in_sizes, int n_in,
                              void* d_out, int out_size, void* d_ws, size_t ws_size,
                              hipStream_t stream) {
    const float* x      = (const float*)d_in[0];
    const float* adj    = (const float*)d_in[1];
    const float* wq     = (const float*)d_in[2];
    const float* wk     = (const float*)d_in[3];
    const float* wv     = (const float*)d_in[4];
    const float* adj2   = (const float*)d_in[5];
    const float* conv_w = (const float*)d_in[6];
    const float* gamma  = (const float*)d_in[7];
    const float* beta   = (const float*)d_in[8];
    const float* mean   = (const float*)d_in[9];
    const float* var    = (const float*)d_in[10];
    char* ws   = (char*)d_ws;
    float* outp = (float*)d_out;

    const int B = in_sizes[0] / (DD * TT * NJ);

    prep_kernel<<<(PREP_ITEMS + 255) / 256, 256, 0, stream>>>(
        adj, wq, wk, wv, adj2, conv_w, gamma, beta, mean, var, ws);

    dim3 grid(TT / 2, B);
    gab_main<<<grid, 256, 0, stream>>>(x, ws, outp);
}